// Round 4
// baseline (836.265 us; speedup 1.0000x reference)
//
#include <hip/hip_runtime.h>
#include <hip/hip_bf16.h>
#include <cfloat>

#define LNUM 4
#define BNUM 16
#define DNUM 768
#define SNUM 1000
#define KNUM 1000
#define KPAD 1024
#define KTNUM 512

typedef __attribute__((ext_vector_type(8))) short s16x8;
typedef __attribute__((ext_vector_type(4))) float f32x4;

__device__ __forceinline__ unsigned short bfb(float x) {
    return __builtin_bit_cast(unsigned short, (__bf16)x);
}
__device__ __forceinline__ float bf2f(unsigned short u) {
    return __builtin_bit_cast(float, ((unsigned int)u) << 16);
}
__device__ __forceinline__ void ins4(unsigned int& t0, unsigned int& t1,
                                     unsigned int& t2, unsigned int& t3, unsigned int key) {
    if (key < t3) {
        bool b2 = key < t2, b1 = key < t1, b0 = key < t0;
        t3 = b2 ? t2 : key;
        t2 = b1 ? t1 : (b2 ? key : t2);
        t1 = b0 ? t0 : (b1 ? key : t1);
        t0 = b0 ? key : t0;
    }
}
__device__ __forceinline__ float keyscore(unsigned int key) {
    unsigned int v = key & ~1023u;
    unsigned int u = (v & 0x80000000u) ? (v ^ 0x80000000u) : ~v;
    return __builtin_bit_cast(float, u);
}

// ---------------- zero tie counter ----------------
__global__ void zero_kernel(int* cnt) { *cnt = 0; }

// ---------------- centers fp32 -> bf16 hi/lo, padded to KPAD rows ----------------
__global__ void prep_kernel(const float* __restrict__ centers,
                            unsigned short* __restrict__ cb_hi,
                            unsigned short* __restrict__ cb_lo) {
    size_t i8 = ((size_t)blockIdx.x * 256 + threadIdx.x) * 8;
    int l  = (int)(i8 / ((size_t)KPAD * DNUM));
    size_t rem = i8 % ((size_t)KPAD * DNUM);
    int kk = (int)(rem / DNUM);
    int d  = (int)(rem % DNUM);
    s16x8 vh = 0, vl = 0;
    if (kk < KNUM) {
        const float* src = centers + ((size_t)l * KNUM + kk) * DNUM + d;
        float4 x0 = *(const float4*)src;
        float4 x1 = *(const float4*)(src + 4);
        float xs[8] = {x0.x, x0.y, x0.z, x0.w, x1.x, x1.y, x1.z, x1.w};
#pragma unroll
        for (int i = 0; i < 8; ++i) {
            unsigned short hb = bfb(xs[i]);
            vh[i] = (short)hb;
            vl[i] = (short)bfb(xs[i] - bf2f(hb));
        }
    }
    *(s16x8*)&cb_hi[i8] = vh;
    *(s16x8*)&cb_lo[i8] = vl;
}

// ---------------- c2 = ||c||^2 (padded rows -> huge) ----------------
__global__ void c2_kernel(const float* __restrict__ centers, float* __restrict__ c2p) {
    int row  = blockIdx.x;          // 0..L*KPAD-1
    int l    = row >> 10;
    int kk   = row & (KPAD - 1);
    int lane = threadIdx.x;
    if (kk >= KNUM) { if (lane == 0) c2p[row] = 3.0e38f; return; }
    const float* cr = centers + ((size_t)l * KNUM + kk) * DNUM;
    float s = 0.f;
    for (int d = lane; d < DNUM; d += 64) s += cr[d] * cr[d];
#pragma unroll
    for (int m = 32; m >= 1; m >>= 1) s += __shfl_xor(s, m);
    if (lane == 0) c2p[row] = s;
}

// ---------------- token kernel: 16x16x32 bf16 MFMA + XOR-swizzled LDS ----------------
// block tile 256k x 128s, 4 waves; wave w owns k rows [w*64, w*64+64), all 128 s cols
__global__ __launch_bounds__(256, 2)
void token_kernel(const float* __restrict__ h, const unsigned short* __restrict__ cb_hi,
                  const float* __restrict__ c2p, float* __restrict__ out_tokens_f,
                  int* __restrict__ ws_tokens, int* __restrict__ tie_cnt,
                  int4* __restrict__ tie_buf) {
    __shared__ unsigned short A_sh[256 * 64];      // [k][8 slots of 8 bf16], slot-swizzled
    __shared__ unsigned short B_sh[128 * 64];      // [s][8 slots], slot-swizzled
    __shared__ float c2_sh[256];
    __shared__ unsigned int tk_lds[4][128][4];

    const int tid  = threadIdx.x;
    const int lane = tid & 63;
    const int w    = tid >> 6;
    const int ln15 = lane & 15;
    const int lg   = lane >> 4;          // 0..3  (k-group within fragment)

    const int stile = blockIdx.x;        // 0..7
    const int lb    = blockIdx.y;        // l*16+b
    const int l     = lb >> 4;
    const int bi    = lb & 15;
    const int s0    = stile * 128;

    const unsigned short* cbl = cb_hi + (size_t)l * KPAD * DNUM;
    const float* Hb = h + (size_t)lb * DNUM * SNUM;

    int rowA[4], colB[8], hB[8];
    const int hA = ln15 & 7;
#pragma unroll
    for (int fi = 0; fi < 4; ++fi) rowA[fi] = w * 64 + fi * 16 + ln15;
#pragma unroll
    for (int fj = 0; fj < 8; ++fj) {
        colB[fj] = fj * 16 + ln15;
        hB[fj] = (colB[fj] ^ (colB[fj] >> 2)) & 7;
    }

    unsigned int tk4[8][4];
#pragma unroll
    for (int fj = 0; fj < 8; ++fj)
#pragma unroll
        for (int r = 0; r < 4; ++r) tk4[fj][r] = 0xFFFFFFFFu;

    for (int kb = 0; kb < KPAD; kb += 256) {
        f32x4 acc[4][8];
#pragma unroll
        for (int fi = 0; fi < 4; ++fi)
#pragma unroll
            for (int fj = 0; fj < 8; ++fj)
#pragma unroll
                for (int r = 0; r < 4; ++r) acc[fi][fj][r] = 0.f;

        for (int c = 0; c < 12; ++c) {
            const int d0 = c * 64;
            __syncthreads();
            // ---- stage A: 256 k-rows x 64 d, slot-swizzled by (row&7)
            {
                const int slot = tid & 7;
                const int rb   = tid >> 3;     // 0..31
#pragma unroll
                for (int j = 0; j < 8; ++j) {
                    int krow = rb + 32 * j;
                    *(int4*)&A_sh[krow * 64 + ((slot ^ (krow & 7)) << 3)] =
                        *(const int4*)(cbl + (size_t)(kb + krow) * DNUM + d0 + slot * 8);
                }
            }
            // ---- stage B: transpose+convert h [d][s] -> B_sh [s][d], slot-swizzled
            {
#pragma unroll
                for (int p = 0; p < 4; ++p) {
                    int dp = ((tid >> 5) << 1) + (p << 4);   // even d in [0,64)
                    int s4 = (tid & 31) << 2;                // 0..124
                    int sg = s0 + s4;
                    float4 f0, f1;
                    if (sg < SNUM) {
                        f0 = *(const float4*)(Hb + (size_t)(d0 + dp) * SNUM + sg);
                        f1 = *(const float4*)(Hb + (size_t)(d0 + dp + 1) * SNUM + sg);
                    } else {
                        f0 = make_float4(0.f, 0.f, 0.f, 0.f); f1 = f0;
                    }
                    float a0[4] = {f0.x, f0.y, f0.z, f0.w};
                    float a1[4] = {f1.x, f1.y, f1.z, f1.w};
                    const int slot = dp >> 3, doff = dp & 7;
#pragma unroll
                    for (int ii = 0; ii < 4; ++ii) {
                        int s = s4 + ii;
                        int phys = slot ^ ((s ^ (s >> 2)) & 7);
                        unsigned int pk = (unsigned int)bfb(a0[ii]) | ((unsigned int)bfb(a1[ii]) << 16);
                        *(unsigned int*)&B_sh[s * 64 + (phys << 3) + doff] = pk;
                    }
                }
            }
            if (c == 0) c2_sh[tid] = c2p[l * KPAD + kb + tid];
            __syncthreads();
            // ---- compute: 2 K-steps x (4 x 8) MFMA
#pragma unroll
            for (int t = 0; t < 2; ++t) {
                const int g = (t << 2) | lg;      // global slot 0..7
                s16x8 av[4], bv[8];
#pragma unroll
                for (int fi = 0; fi < 4; ++fi)
                    av[fi] = *(const s16x8*)&A_sh[rowA[fi] * 64 + ((g ^ hA) << 3)];
#pragma unroll
                for (int fj = 0; fj < 8; ++fj)
                    bv[fj] = *(const s16x8*)&B_sh[colB[fj] * 64 + ((g ^ hB[fj]) << 3)];
#pragma unroll
                for (int fi = 0; fi < 4; ++fi)
#pragma unroll
                    for (int fj = 0; fj < 8; ++fj)
                        acc[fi][fj] = __builtin_amdgcn_mfma_f32_16x16x32_bf16(av[fi], bv[fj], acc[fi][fj], 0, 0, 0);
            }
        }
        // ---- epilogue: scores -> packed keys -> top-4 insert
#pragma unroll
        for (int fi = 0; fi < 4; ++fi) {
#pragma unroll
            for (int r = 0; r < 4; ++r) {
                const int klocal = w * 64 + fi * 16 + 4 * lg + r;   // C/D row = 4*(lane>>4)+reg
                const float c2v = c2_sh[klocal];
                const unsigned int kg = (unsigned int)(kb + klocal);
#pragma unroll
                for (int fj = 0; fj < 8; ++fj) {
                    float sc = fmaf(-2.f, acc[fi][fj][r], c2v);
                    unsigned int u = __builtin_bit_cast(unsigned int, sc);
                    u ^= 0x80000000u | (unsigned int)((int)u >> 31);
                    unsigned int key = (u & ~1023u) | kg;
                    ins4(tk4[fj][0], tk4[fj][1], tk4[fj][2], tk4[fj][3], key);
                }
            }
        }
    }
    // ---- intra-wave merge across the 4 lane-groups (same columns)
#pragma unroll
    for (int m = 16; m <= 32; m <<= 1) {
#pragma unroll
        for (int fj = 0; fj < 8; ++fj) {
            unsigned int o0 = (unsigned int)__shfl_xor((int)tk4[fj][0], m);
            unsigned int o1 = (unsigned int)__shfl_xor((int)tk4[fj][1], m);
            unsigned int o2 = (unsigned int)__shfl_xor((int)tk4[fj][2], m);
            unsigned int o3 = (unsigned int)__shfl_xor((int)tk4[fj][3], m);
            ins4(tk4[fj][0], tk4[fj][1], tk4[fj][2], tk4[fj][3], o0);
            ins4(tk4[fj][0], tk4[fj][1], tk4[fj][2], tk4[fj][3], o1);
            ins4(tk4[fj][0], tk4[fj][1], tk4[fj][2], tk4[fj][3], o2);
            ins4(tk4[fj][0], tk4[fj][1], tk4[fj][2], tk4[fj][3], o3);
        }
    }
    if (lg == 0) {
#pragma unroll
        for (int fj = 0; fj < 8; ++fj) {
            uint4 v = make_uint4(tk4[fj][0], tk4[fj][1], tk4[fj][2], tk4[fj][3]);
            *(uint4*)&tk_lds[w][fj * 16 + ln15][0] = v;
        }
    }
    __syncthreads();
    // ---- cross-wave merge + write (one thread per column)
    if (tid < 128) {
        const int col = tid;
        uint4 v0 = *(const uint4*)&tk_lds[0][col][0];
        unsigned int t0 = v0.x, t1 = v0.y, t2 = v0.z, t3 = v0.w;
#pragma unroll
        for (int ww = 1; ww < 4; ++ww) {
            uint4 v = *(const uint4*)&tk_lds[ww][col][0];
            ins4(t0, t1, t2, t3, v.x);
            ins4(t0, t1, t2, t3, v.y);
            ins4(t0, t1, t2, t3, v.z);
            ins4(t0, t1, t2, t3, v.w);
        }
        const int sg = s0 + col;
        if (sg < SNUM) {
            const int tok = (int)(t0 & 1023u);
            out_tokens_f[((size_t)bi * SNUM + sg) * LNUM + l] = (float)tok;
            ws_tokens[((size_t)l * BNUM + bi) * SNUM + sg] = tok;
            if (keyscore(t1) - keyscore(t0) < 1.25f) {
                int idx = atomicAdd(tie_cnt, 1);
                if (idx < 65536) {
                    tie_buf[idx] = make_int4((lb << 10) | sg,
                                             (int)((t0 & 1023u) | ((t1 & 1023u) << 16)),
                                             (int)((t2 & 1023u) | ((t3 & 1023u) << 16)), 0);
                }
            }
        }
    }
}

// ---------------- fp64 rescore of near-ties ----------------
__global__ void rescore_kernel(const float* __restrict__ h, const float* __restrict__ centers,
                               const int* __restrict__ tie_cnt, const int4* __restrict__ tie_buf,
                               float* __restrict__ out_tokens_f, int* __restrict__ ws_tokens) {
    const int lane = threadIdx.x & 63;
    const int wave_id = blockIdx.x * 4 + (threadIdx.x >> 6);
    int cnt = *tie_cnt;
    if (cnt > 65536) cnt = 65536;
    for (int e = wave_id; e < cnt; e += 256 * 4) {
        int4 ent = tie_buf[e];
        const int sg = ent.x & 1023, lb = ent.x >> 10;
        const int l = lb >> 4, bi = lb & 15;
        const int g = lane >> 4;
        int kc = (g == 0) ? (ent.y & 0xFFFF) : (g == 1) ? ((ent.y >> 16) & 0xFFFF)
               : (g == 2) ? (ent.z & 0xFFFF) : ((ent.z >> 16) & 0xFFFF);
        const float* cp = centers + ((size_t)l * KNUM + kc) * DNUM;
        const float* xp = h + (size_t)lb * DNUM * SNUM + sg;
        double xc = 0.0, cc = 0.0;
        for (int d = (lane & 15); d < DNUM; d += 16) {
            double cv = (double)cp[d];
            double xv = (double)xp[(size_t)d * SNUM];
            xc = fma(cv, xv, xc);
            cc = fma(cv, cv, cc);
        }
        double sc = cc - 2.0 * xc;
#pragma unroll
        for (int m = 1; m <= 8; m <<= 1) sc += __shfl_xor(sc, m);
        double s0 = __shfl(sc, 0), s1 = __shfl(sc, 16), s2 = __shfl(sc, 32), s3 = __shfl(sc, 48);
        if (lane == 0) {
            int k0 = ent.y & 0xFFFF, k1 = (ent.y >> 16) & 0xFFFF;
            int k2 = ent.z & 0xFFFF, k3 = (ent.z >> 16) & 0xFFFF;
            double bs = s0; int bk = k0;
            if (s1 < bs || (s1 == bs && k1 < bk)) { bs = s1; bk = k1; }
            if (s2 < bs || (s2 == bs && k2 < bk)) { bs = s2; bk = k2; }
            if (s3 < bs || (s3 == bs && k3 < bk)) { bs = s3; bk = k3; }
            out_tokens_f[((size_t)bi * SNUM + sg) * LNUM + l] = (float)bk;
            ws_tokens[((size_t)l * BNUM + bi) * SNUM + sg] = bk;
        }
    }
}

// ---------------- proj: P[l] = centers @ W + b, MFMA bf16 hi/lo 3-term ----------------
// block tile 64m x 128kt, 4 waves; wave w owns m rows [w*16, w*16+16), all 128 kt cols
__global__ __launch_bounds__(256, 2)
void proj_kernel(const unsigned short* __restrict__ cb_hi, const unsigned short* __restrict__ cb_lo,
                 const float* __restrict__ W, const float* __restrict__ bvec,
                 float* __restrict__ P) {
    __shared__ unsigned short Ah_sh[64 * 64], Al_sh[64 * 64];     // 8 KB each
    __shared__ unsigned short Bh_sh[128 * 64], Bl_sh[128 * 64];   // 16 KB each

    const int tid  = threadIdx.x;
    const int lane = tid & 63;
    const int w    = tid >> 6;
    const int ln15 = lane & 15;
    const int lg   = lane >> 4;

    const int nt = blockIdx.x;    // 0..3  -> n0
    const int mt = blockIdx.y;    // 0..15 -> m0
    const int l  = blockIdx.z;
    const int n0 = nt * 128, m0 = mt * 64;

    const unsigned short* cbh = cb_hi + (size_t)l * KPAD * DNUM;
    const unsigned short* cbL = cb_lo + (size_t)l * KPAD * DNUM;
    const float* Wb = W + (size_t)l * DNUM * KTNUM;

    const int rowA = w * 16 + ln15;
    const int hA   = rowA & 7;
    int colB[8], hB[8];
#pragma unroll
    for (int fj = 0; fj < 8; ++fj) {
        colB[fj] = fj * 16 + ln15;
        hB[fj] = (colB[fj] ^ (colB[fj] >> 2)) & 7;
    }

    f32x4 acc[8];
#pragma unroll
    for (int fj = 0; fj < 8; ++fj)
#pragma unroll
        for (int r = 0; r < 4; ++r) acc[fj][r] = 0.f;

    for (int c = 0; c < 12; ++c) {
        const int d0 = c * 64;
        __syncthreads();
        {   // stage A hi+lo: 64 rows x 8 slots, slot-swizzled
            const int slot = tid & 7;
            const int rb   = tid >> 3;     // 0..31
#pragma unroll
            for (int j = 0; j < 2; ++j) {
                int krow = rb + 32 * j;
                size_t so = (size_t)(m0 + krow) * DNUM + d0 + slot * 8;
                int dst = krow * 64 + ((slot ^ (krow & 7)) << 3);
                *(int4*)&Ah_sh[dst] = *(const int4*)(cbh + so);
                *(int4*)&Al_sh[dst] = *(const int4*)(cbL + so);
            }
        }
        {   // stage B: W [d][kt] -> [kt][d] bf16 hi/lo, slot-swizzled
#pragma unroll
            for (int p = 0; p < 4; ++p) {
                int dp = ((tid >> 5) << 1) + (p << 4);
                int s4 = (tid & 31) << 2;
                float4 f0 = *(const float4*)(Wb + (size_t)(d0 + dp) * KTNUM + n0 + s4);
                float4 f1 = *(const float4*)(Wb + (size_t)(d0 + dp + 1) * KTNUM + n0 + s4);
                float a0[4] = {f0.x, f0.y, f0.z, f0.w};
                float a1[4] = {f1.x, f1.y, f1.z, f1.w};
                const int slot = dp >> 3, doff = dp & 7;
#pragma unroll
                for (int ii = 0; ii < 4; ++ii) {
                    int s = s4 + ii;
                    int phys = slot ^ ((s ^ (s >> 2)) & 7);
                    unsigned short h0 = bfb(a0[ii]), h1 = bfb(a1[ii]);
                    unsigned short l0 = bfb(a0[ii] - bf2f(h0)), l1 = bfb(a1[ii] - bf2f(h1));
                    int off = s * 64 + (phys << 3) + doff;
                    *(unsigned int*)&Bh_sh[off] = (unsigned int)h0 | ((unsigned int)h1 << 16);
                    *(unsigned int*)&Bl_sh[off] = (unsigned int)l0 | ((unsigned int)l1 << 16);
                }
            }
        }
        __syncthreads();
#pragma unroll
        for (int t = 0; t < 2; ++t) {
            const int g = (t << 2) | lg;
            const int aoff = rowA * 64 + ((g ^ hA) << 3);
            s16x8 ah = *(const s16x8*)&Ah_sh[aoff];
            s16x8 al = *(const s16x8*)&Al_sh[aoff];
#pragma unroll
            for (int fj = 0; fj < 8; ++fj) {
                const int boff = colB[fj] * 64 + ((g ^ hB[fj]) << 3);
                s16x8 bh = *(const s16x8*)&Bh_sh[boff];
                s16x8 bl = *(const s16x8*)&Bl_sh[boff];
                acc[fj] = __builtin_amdgcn_mfma_f32_16x16x32_bf16(ah, bh, acc[fj], 0, 0, 0);
                acc[fj] = __builtin_amdgcn_mfma_f32_16x16x32_bf16(ah, bl, acc[fj], 0, 0, 0);
                acc[fj] = __builtin_amdgcn_mfma_f32_16x16x32_bf16(al, bh, acc[fj], 0, 0, 0);
            }
        }
    }
    // epilogue: + bias, store (C/D: col=ln15, row=4*lg+r)
#pragma unroll
    for (int fj = 0; fj < 8; ++fj) {
        const int ktcol = n0 + colB[fj];
        const float bb = bvec[l * KTNUM + ktcol];
#pragma unroll
        for (int r = 0; r < 4; ++r) {
            const int mg = m0 + w * 16 + 4 * lg + r;
            P[((size_t)l * KPAD + mg) * KTNUM + ktcol] = acc[fj][r] + bb;
        }
    }
}

// ---------------- gather: out[b][s][l][:] = P[l][tok] ----------------
__global__ void gather_kernel(const float* __restrict__ P, const int* __restrict__ ws_tokens,
                              float* __restrict__ out_embs) {
    __shared__ int toks[LNUM];
    int bs  = blockIdx.x;
    int bi  = bs / SNUM;
    int s   = bs % SNUM;
    int tid = threadIdx.x;
    if (tid < LNUM) toks[tid] = ws_tokens[((size_t)tid * BNUM + bi) * SNUM + s];
    __syncthreads();
    const float4* P4 = (const float4*)P;
    float4* O4 = (float4*)out_embs + (size_t)bs * (LNUM * KTNUM / 4);
#pragma unroll
    for (int r = 0; r < 2; ++r) {
        int idx = tid + r * 256;
        int l   = idx >> 7;
        int j4  = idx & 127;
        O4[idx] = P4[(((size_t)l * KPAD + toks[l]) * KTNUM >> 2) + j4];
    }
}

extern "C" void kernel_launch(void* const* d_in, const int* in_sizes, int n_in,
                              void* d_out, int out_size, void* d_ws, size_t ws_size,
                              hipStream_t stream) {
    const float* h       = (const float*)d_in[0];
    const float* centers = (const float*)d_in[1];
    const float* W       = (const float*)d_in[2];
    const float* b       = (const float*)d_in[3];

    float* out        = (float*)d_out;
    float* out_tokens = out;
    float* out_embs   = out + (size_t)BNUM * SNUM * LNUM;

    char* ws = (char*)d_ws;
    int*            ws_tokens = (int*)ws;                              // 256 KB @ 0
    float*          c2p       = (float*)(ws + (256 << 10));            // 16 KB
    int*            tie_cnt   = (int*)(ws + (288 << 10));
    int4*           tie_buf   = (int4*)(ws + (320 << 10));             // 1 MB
    float*          P         = (float*)(ws + (1536 << 10));           // 8.39 MB
    unsigned short* cb_hi     = (unsigned short*)(ws + (10496 << 10)); // 6.29 MB
    unsigned short* cb_lo     = (unsigned short*)(ws + (17408 << 10)); // 6.29 MB

    zero_kernel<<<1, 1, 0, stream>>>(tie_cnt);
    prep_kernel<<<dim3(1536), dim3(256), 0, stream>>>(centers, cb_hi, cb_lo);
    c2_kernel<<<dim3(LNUM * KPAD), dim3(64), 0, stream>>>(centers, c2p);
    token_kernel<<<dim3(8, 64), dim3(256), 0, stream>>>(h, cb_hi, c2p, out_tokens,
                                                        ws_tokens, tie_cnt, tie_buf);
    rescore_kernel<<<dim3(256), dim3(256), 0, stream>>>(h, centers, tie_cnt, tie_buf,
                                                        out_tokens, ws_tokens);
    proj_kernel<<<dim3(4, 16, LNUM), dim3(256), 0, stream>>>(cb_hi, cb_lo, W, b, P);
    gather_kernel<<<dim3(BNUM * SNUM), dim3(256), 0, stream>>>(P, ws_tokens, out_embs);
}

// Round 5
// 480.288 us; speedup vs baseline: 1.7412x; 1.7412x over previous
//
#include <hip/hip_runtime.h>
#include <hip/hip_bf16.h>
#include <cfloat>

#define LNUM 4
#define BNUM 16
#define DNUM 768
#define SNUM 1000
#define SPAD 1024
#define KNUM 1000
#define KPAD 1024
#define KTNUM 512
#define LSTRIDE 72   // LDS row stride in shorts: 144 B, 16B-aligned, 4-bank row shift

typedef __attribute__((ext_vector_type(8))) short s16x8;
typedef __attribute__((ext_vector_type(4))) float f32x4;

__device__ __forceinline__ unsigned short bfb(float x) {
    return __builtin_bit_cast(unsigned short, (__bf16)x);
}
__device__ __forceinline__ float bf2f(unsigned short u) {
    return __builtin_bit_cast(float, ((unsigned int)u) << 16);
}
__device__ __forceinline__ void ins4(unsigned int& t0, unsigned int& t1,
                                     unsigned int& t2, unsigned int& t3, unsigned int key) {
    if (key < t3) {
        bool b2 = key < t2, b1 = key < t1, b0 = key < t0;
        t3 = b2 ? t2 : key;
        t2 = b1 ? t1 : (b2 ? key : t2);
        t1 = b0 ? t0 : (b1 ? key : t1);
        t0 = b0 ? key : t0;
    }
}
__device__ __forceinline__ float keyscore(unsigned int key) {
    unsigned int v = key & ~1023u;
    unsigned int u = (v & 0x80000000u) ? (v ^ 0x80000000u) : ~v;
    return __builtin_bit_cast(float, u);
}

// ---------------- zero tie counter ----------------
__global__ void zero_kernel(int* cnt) { *cnt = 0; }

// ---------------- centers fp32 -> bf16 hi/lo, padded to KPAD rows ----------------
__global__ void prep_kernel(const float* __restrict__ centers,
                            unsigned short* __restrict__ cb_hi,
                            unsigned short* __restrict__ cb_lo) {
    size_t i8 = ((size_t)blockIdx.x * 256 + threadIdx.x) * 8;
    int l  = (int)(i8 / ((size_t)KPAD * DNUM));
    size_t rem = i8 % ((size_t)KPAD * DNUM);
    int kk = (int)(rem / DNUM);
    int d  = (int)(rem % DNUM);
    s16x8 vh = 0, vl = 0;
    if (kk < KNUM) {
        const float* src = centers + ((size_t)l * KNUM + kk) * DNUM + d;
        float4 x0 = *(const float4*)src;
        float4 x1 = *(const float4*)(src + 4);
        float xs[8] = {x0.x, x0.y, x0.z, x0.w, x1.x, x1.y, x1.z, x1.w};
#pragma unroll
        for (int i = 0; i < 8; ++i) {
            unsigned short hb = bfb(xs[i]);
            vh[i] = (short)hb;
            vl[i] = (short)bfb(xs[i] - bf2f(hb));
        }
    }
    *(s16x8*)&cb_hi[i8] = vh;
    *(s16x8*)&cb_lo[i8] = vl;
}

// ---------------- c2 = ||c||^2 (padded rows -> huge) ----------------
__global__ void c2_kernel(const float* __restrict__ centers, float* __restrict__ c2p) {
    int row  = blockIdx.x;          // 0..L*KPAD-1
    int l    = row >> 10;
    int kk   = row & (KPAD - 1);
    int lane = threadIdx.x;
    if (kk >= KNUM) { if (lane == 0) c2p[row] = 3.0e38f; return; }
    const float* cr = centers + ((size_t)l * KNUM + kk) * DNUM;
    float s = 0.f;
    for (int d = lane; d < DNUM; d += 64) s += cr[d] * cr[d];
#pragma unroll
    for (int m = 32; m >= 1; m >>= 1) s += __shfl_xor(s, m);
    if (lane == 0) c2p[row] = s;
}

// ---------------- trans: h [lb][d][s] fp32 -> hT2 [lb2][s(1024)][d] bf16 (2 layers) ----
__global__ void trans_kernel(const float* __restrict__ h, unsigned short* __restrict__ hT2,
                             int lpair) {
    __shared__ unsigned short T[64][LSTRIDE];
    const int st  = blockIdx.x;       // s tile 0..15
    const int dt  = blockIdx.y;       // d tile 0..11
    const int lb2 = blockIdx.z;       // 0..31
    const int l   = lpair * 2 + (lb2 >> 4);
    const int bi  = lb2 & 15;
    const int lb  = l * 16 + bi;
    const int s0  = st * 64, d0 = dt * 64;
    const int tid = threadIdx.x;

    const float* src = h + (size_t)lb * DNUM * SNUM;
    {   // read: thread -> row dd, 16 s values; convert; scatter into T[ss][dd]
        const int dd = tid >> 2, q = tid & 3;
        unsigned short vals[16];
#pragma unroll
        for (int i = 0; i < 4; ++i) {
            int ss = q * 16 + i * 4;
            int sg = s0 + ss;
            float4 v = (sg < SNUM) ? *(const float4*)&src[(size_t)(d0 + dd) * SNUM + sg]
                                   : make_float4(0.f, 0.f, 0.f, 0.f);
            vals[i * 4 + 0] = bfb(v.x); vals[i * 4 + 1] = bfb(v.y);
            vals[i * 4 + 2] = bfb(v.z); vals[i * 4 + 3] = bfb(v.w);
        }
#pragma unroll
        for (int i = 0; i < 16; ++i) T[q * 16 + i][dd] = vals[i];
    }
    __syncthreads();
    {   // write: thread -> output row s0+ss2, 2 slots of 8 d
        const int ss2 = tid >> 2, slot2 = tid & 3;
        unsigned short* dst = hT2 + (size_t)lb2 * SPAD * DNUM + (size_t)(s0 + ss2) * DNUM + d0;
#pragma unroll
        for (int j = 0; j < 2; ++j) {
            int slot = slot2 + 4 * j;
            *(int4*)&dst[slot * 8] = *(const int4*)&T[ss2][slot * 8];
        }
    }
}

// ---------------- token kernel: 16x16x32 bf16 MFMA, padded-stride LDS, 2 layers ------
// block tile 256k x 64s, 4 waves; wave w owns k rows [w*64, w*64+64), all 64 s cols
__global__ __launch_bounds__(256, 2)
void token_kernel(const unsigned short* __restrict__ hT2, const unsigned short* __restrict__ cb_hi,
                  const float* __restrict__ c2p, float* __restrict__ out_tokens_f,
                  int* __restrict__ ws_tokens, int* __restrict__ tie_cnt,
                  int4* __restrict__ tie_buf, int lpair) {
    __shared__ unsigned short A_sh[256 * LSTRIDE];   // 36 KB
    __shared__ unsigned short B_sh[64 * LSTRIDE];    // 9 KB
    __shared__ float c2_sh[256];
    __shared__ unsigned int tk_lds[4][64][4];        // 4 KB

    const int tid  = threadIdx.x;
    const int lane = tid & 63;
    const int w    = tid >> 6;
    const int ln15 = lane & 15;
    const int lg   = lane >> 4;          // 0..3 (k-group within fragment)

    const int stile = blockIdx.x;        // 0..15
    const int lb2   = blockIdx.y;        // 0..31
    const int l     = lpair * 2 + (lb2 >> 4);
    const int bi    = lb2 & 15;
    const int s0    = stile * 64;

    const unsigned short* cbl = cb_hi + (size_t)l * KPAD * DNUM;
    const unsigned short* Hb  = hT2 + (size_t)lb2 * SPAD * DNUM;   // [s][d] bf16

    unsigned int tk4[4][4];
#pragma unroll
    for (int fj = 0; fj < 4; ++fj)
#pragma unroll
        for (int r = 0; r < 4; ++r) tk4[fj][r] = 0xFFFFFFFFu;

    for (int kb = 0; kb < KPAD; kb += 256) {
        f32x4 acc[4][4];
#pragma unroll
        for (int fi = 0; fi < 4; ++fi)
#pragma unroll
            for (int fj = 0; fj < 4; ++fj)
#pragma unroll
                for (int r = 0; r < 4; ++r) acc[fi][fj][r] = 0.f;

        for (int c = 0; c < 12; ++c) {
            const int d0 = c * 64;
            __syncthreads();
            {   // stage A: 256 k-rows x 8 slots, linear slots, padded stride
                const int slot = tid & 7;
                const int rb   = tid >> 3;     // 0..31
#pragma unroll
                for (int j = 0; j < 8; ++j) {
                    int krow = rb + 32 * j;
                    *(int4*)&A_sh[krow * LSTRIDE + slot * 8] =
                        *(const int4*)(cbl + (size_t)(kb + krow) * DNUM + d0 + slot * 8);
                }
            }
            {   // stage B: 64 s-rows x 8 slots from hT (already [s][d] bf16)
                const int slot = tid & 7;
                const int rb   = tid >> 3;     // 0..31
#pragma unroll
                for (int j = 0; j < 2; ++j) {
                    int srow = rb + 32 * j;
                    *(int4*)&B_sh[srow * LSTRIDE + slot * 8] =
                        *(const int4*)(Hb + (size_t)(s0 + srow) * DNUM + d0 + slot * 8);
                }
            }
            if (c == 0) c2_sh[tid] = c2p[l * KPAD + kb + tid];
            __syncthreads();
            // compute: 2 K-steps x (4 x 4) MFMA; offsets = per-lane base + immediates
#pragma unroll
            for (int t = 0; t < 2; ++t) {
                const int doff = 32 * t + 8 * lg;
                s16x8 av[4], bv[4];
#pragma unroll
                for (int fi = 0; fi < 4; ++fi)
                    av[fi] = *(const s16x8*)&A_sh[(w * 64 + fi * 16 + ln15) * LSTRIDE + doff];
#pragma unroll
                for (int fj = 0; fj < 4; ++fj)
                    bv[fj] = *(const s16x8*)&B_sh[(fj * 16 + ln15) * LSTRIDE + doff];
#pragma unroll
                for (int fi = 0; fi < 4; ++fi)
#pragma unroll
                    for (int fj = 0; fj < 4; ++fj)
                        acc[fi][fj] = __builtin_amdgcn_mfma_f32_16x16x32_bf16(av[fi], bv[fj], acc[fi][fj], 0, 0, 0);
            }
        }
        // epilogue: scores -> packed keys -> top-4 insert
#pragma unroll
        for (int fi = 0; fi < 4; ++fi) {
#pragma unroll
            for (int r = 0; r < 4; ++r) {
                const int klocal = w * 64 + fi * 16 + 4 * lg + r;   // C/D row = 4*(lane>>4)+reg
                const float c2v = c2_sh[klocal];
                const unsigned int kg = (unsigned int)(kb + klocal);
#pragma unroll
                for (int fj = 0; fj < 4; ++fj) {
                    float sc = fmaf(-2.f, acc[fi][fj][r], c2v);
                    unsigned int u = __builtin_bit_cast(unsigned int, sc);
                    u ^= 0x80000000u | (unsigned int)((int)u >> 31);
                    unsigned int key = (u & ~1023u) | kg;
                    ins4(tk4[fj][0], tk4[fj][1], tk4[fj][2], tk4[fj][3], key);
                }
            }
        }
    }
    // intra-wave merge across the 4 lane-groups (same columns)
#pragma unroll
    for (int m = 16; m <= 32; m <<= 1) {
#pragma unroll
        for (int fj = 0; fj < 4; ++fj) {
            unsigned int o0 = (unsigned int)__shfl_xor((int)tk4[fj][0], m);
            unsigned int o1 = (unsigned int)__shfl_xor((int)tk4[fj][1], m);
            unsigned int o2 = (unsigned int)__shfl_xor((int)tk4[fj][2], m);
            unsigned int o3 = (unsigned int)__shfl_xor((int)tk4[fj][3], m);
            ins4(tk4[fj][0], tk4[fj][1], tk4[fj][2], tk4[fj][3], o0);
            ins4(tk4[fj][0], tk4[fj][1], tk4[fj][2], tk4[fj][3], o1);
            ins4(tk4[fj][0], tk4[fj][1], tk4[fj][2], tk4[fj][3], o2);
            ins4(tk4[fj][0], tk4[fj][1], tk4[fj][2], tk4[fj][3], o3);
        }
    }
    if (lg == 0) {
#pragma unroll
        for (int fj = 0; fj < 4; ++fj) {
            uint4 v = make_uint4(tk4[fj][0], tk4[fj][1], tk4[fj][2], tk4[fj][3]);
            *(uint4*)&tk_lds[w][fj * 16 + ln15][0] = v;
        }
    }
    __syncthreads();
    // cross-wave merge + write (one thread per column)
    if (tid < 64) {
        const int col = tid;
        uint4 v0 = *(const uint4*)&tk_lds[0][col][0];
        unsigned int t0 = v0.x, t1 = v0.y, t2 = v0.z, t3 = v0.w;
#pragma unroll
        for (int ww = 1; ww < 4; ++ww) {
            uint4 v = *(const uint4*)&tk_lds[ww][col][0];
            ins4(t0, t1, t2, t3, v.x);
            ins4(t0, t1, t2, t3, v.y);
            ins4(t0, t1, t2, t3, v.z);
            ins4(t0, t1, t2, t3, v.w);
        }
        const int sg = s0 + col;
        if (sg < SNUM) {
            const int tok = (int)(t0 & 1023u);
            out_tokens_f[((size_t)bi * SNUM + sg) * LNUM + l] = (float)tok;
            ws_tokens[((size_t)l * BNUM + bi) * SNUM + sg] = tok;
            if (keyscore(t1) - keyscore(t0) < 1.25f) {
                int idx = atomicAdd(tie_cnt, 1);
                if (idx < 65536) {
                    int lb = l * 16 + bi;
                    tie_buf[idx] = make_int4((lb << 10) | sg,
                                             (int)((t0 & 1023u) | ((t1 & 1023u) << 16)),
                                             (int)((t2 & 1023u) | ((t3 & 1023u) << 16)), 0);
                }
            }
        }
    }
}

// ---------------- fp64 rescore of near-ties ----------------
__global__ void rescore_kernel(const float* __restrict__ h, const float* __restrict__ centers,
                               const int* __restrict__ tie_cnt, const int4* __restrict__ tie_buf,
                               float* __restrict__ out_tokens_f, int* __restrict__ ws_tokens) {
    const int lane = threadIdx.x & 63;
    const int wave_id = blockIdx.x * 4 + (threadIdx.x >> 6);
    int cnt = *tie_cnt;
    if (cnt > 65536) cnt = 65536;
    for (int e = wave_id; e < cnt; e += 256 * 4) {
        int4 ent = tie_buf[e];
        const int sg = ent.x & 1023, lb = ent.x >> 10;
        const int l = lb >> 4, bi = lb & 15;
        const int g = lane >> 4;
        int kc = (g == 0) ? (ent.y & 0xFFFF) : (g == 1) ? ((ent.y >> 16) & 0xFFFF)
               : (g == 2) ? (ent.z & 0xFFFF) : ((ent.z >> 16) & 0xFFFF);
        const float* cp = centers + ((size_t)l * KNUM + kc) * DNUM;
        const float* xp = h + (size_t)lb * DNUM * SNUM + sg;
        double xc = 0.0, cc = 0.0;
        for (int d = (lane & 15); d < DNUM; d += 16) {
            double cv = (double)cp[d];
            double xv = (double)xp[(size_t)d * SNUM];
            xc = fma(cv, xv, xc);
            cc = fma(cv, cv, cc);
        }
        double sc = cc - 2.0 * xc;
#pragma unroll
        for (int m = 1; m <= 8; m <<= 1) sc += __shfl_xor(sc, m);
        double s0 = __shfl(sc, 0), s1 = __shfl(sc, 16), s2 = __shfl(sc, 32), s3 = __shfl(sc, 48);
        if (lane == 0) {
            int k0 = ent.y & 0xFFFF, k1 = (ent.y >> 16) & 0xFFFF;
            int k2 = ent.z & 0xFFFF, k3 = (ent.z >> 16) & 0xFFFF;
            double bs = s0; int bk = k0;
            if (s1 < bs || (s1 == bs && k1 < bk)) { bs = s1; bk = k1; }
            if (s2 < bs || (s2 == bs && k2 < bk)) { bs = s2; bk = k2; }
            if (s3 < bs || (s3 == bs && k3 < bk)) { bs = s3; bk = k3; }
            out_tokens_f[((size_t)bi * SNUM + sg) * LNUM + l] = (float)bk;
            ws_tokens[((size_t)l * BNUM + bi) * SNUM + sg] = bk;
        }
    }
}

// ---------------- proj: P[l] = centers @ W + b, MFMA bf16 hi/lo 3-term (R4, verified) --
__global__ __launch_bounds__(256, 2)
void proj_kernel(const unsigned short* __restrict__ cb_hi, const unsigned short* __restrict__ cb_lo,
                 const float* __restrict__ W, const float* __restrict__ bvec,
                 float* __restrict__ P) {
    __shared__ unsigned short Ah_sh[64 * 64], Al_sh[64 * 64];
    __shared__ unsigned short Bh_sh[128 * 64], Bl_sh[128 * 64];

    const int tid  = threadIdx.x;
    const int lane = tid & 63;
    const int w    = tid >> 6;
    const int ln15 = lane & 15;
    const int lg   = lane >> 4;

    const int nt = blockIdx.x;    // 0..3  -> n0
    const int mt = blockIdx.y;    // 0..15 -> m0
    const int l  = blockIdx.z;
    const int n0 = nt * 128, m0 = mt * 64;

    const unsigned short* cbh = cb_hi + (size_t)l * KPAD * DNUM;
    const unsigned short* cbL = cb_lo + (size_t)l * KPAD * DNUM;
    const float* Wb = W + (size_t)l * DNUM * KTNUM;

    const int rowA = w * 16 + ln15;
    const int hA   = rowA & 7;
    int colB[8], hB[8];
#pragma unroll
    for (int fj = 0; fj < 8; ++fj) {
        colB[fj] = fj * 16 + ln15;
        hB[fj] = (colB[fj] ^ (colB[fj] >> 2)) & 7;
    }

    f32x4 acc[8];
#pragma unroll
    for (int fj = 0; fj < 8; ++fj)
#pragma unroll
        for (int r = 0; r < 4; ++r) acc[fj][r] = 0.f;

    for (int c = 0; c < 12; ++c) {
        const int d0 = c * 64;
        __syncthreads();
        {   // stage A hi+lo: 64 rows x 8 slots, slot-swizzled
            const int slot = tid & 7;
            const int rb   = tid >> 3;     // 0..31
#pragma unroll
            for (int j = 0; j < 2; ++j) {
                int krow = rb + 32 * j;
                size_t so = (size_t)(m0 + krow) * DNUM + d0 + slot * 8;
                int dst = krow * 64 + ((slot ^ (krow & 7)) << 3);
                *(int4*)&Ah_sh[dst] = *(const int4*)(cbh + so);
                *(int4*)&Al_sh[dst] = *(const int4*)(cbL + so);
            }
        }
        {   // stage B: W [d][kt] -> [kt][d] bf16 hi/lo, slot-swizzled
#pragma unroll
            for (int p = 0; p < 4; ++p) {
                int dp = ((tid >> 5) << 1) + (p << 4);
                int s4 = (tid & 31) << 2;
                float4 f0 = *(const float4*)(Wb + (size_t)(d0 + dp) * KTNUM + n0 + s4);
                float4 f1 = *(const float4*)(Wb + (size_t)(d0 + dp + 1) * KTNUM + n0 + s4);
                float a0[4] = {f0.x, f0.y, f0.z, f0.w};
                float a1[4] = {f1.x, f1.y, f1.z, f1.w};
                const int slot = dp >> 3, doff = dp & 7;
#pragma unroll
                for (int ii = 0; ii < 4; ++ii) {
                    int s = s4 + ii;
                    int phys = slot ^ ((s ^ (s >> 2)) & 7);
                    unsigned short h0 = bfb(a0[ii]), h1 = bfb(a1[ii]);
                    unsigned short l0 = bfb(a0[ii] - bf2f(h0)), l1 = bfb(a1[ii] - bf2f(h1));
                    int off = s * 64 + (phys << 3) + doff;
                    *(unsigned int*)&Bh_sh[off] = (unsigned int)h0 | ((unsigned int)h1 << 16);
                    *(unsigned int*)&Bl_sh[off] = (unsigned int)l0 | ((unsigned int)l1 << 16);
                }
            }
        }
        __syncthreads();
#pragma unroll
        for (int t = 0; t < 2; ++t) {
            const int g = (t << 2) | lg;
            const int aoff = rowA * 64 + ((g ^ hA) << 3);
            s16x8 ah = *(const s16x8*)&Ah_sh[aoff];
            s16x8 al = *(const s16x8*)&Al_sh[aoff];
#pragma unroll
            for (int fj = 0; fj < 8; ++fj) {
                const int boff = colB[fj] * 64 + ((g ^ hB[fj]) << 3);
                s16x8 bh = *(const s16x8*)&Bh_sh[boff];
                s16x8 bl = *(const s16x8*)&Bl_sh[boff];
                acc[fj] = __builtin_amdgcn_mfma_f32_16x16x32_bf16(ah, bh, acc[fj], 0, 0, 0);
                acc[fj] = __builtin_amdgcn_mfma_f32_16x16x32_bf16(ah, bl, acc[fj], 0, 0, 0);
                acc[fj] = __builtin_amdgcn_mfma_f32_16x16x32_bf16(al, bh, acc[fj], 0, 0, 0);
            }
        }
    }
#pragma unroll
    for (int fj = 0; fj < 8; ++fj) {
        const int ktcol = n0 + colB[fj];
        const float bb = bvec[l * KTNUM + ktcol];
#pragma unroll
        for (int r = 0; r < 4; ++r) {
            const int mg = m0 + w * 16 + 4 * lg + r;
            P[((size_t)l * KPAD + mg) * KTNUM + ktcol] = acc[fj][r] + bb;
        }
    }
}

// ---------------- gather: out[b][s][l][:] = P[l][tok] ----------------
__global__ void gather_kernel(const float* __restrict__ P, const int* __restrict__ ws_tokens,
                              float* __restrict__ out_embs) {
    __shared__ int toks[LNUM];
    int bs  = blockIdx.x;
    int bi  = bs / SNUM;
    int s   = bs % SNUM;
    int tid = threadIdx.x;
    if (tid < LNUM) toks[tid] = ws_tokens[((size_t)tid * BNUM + bi) * SNUM + s];
    __syncthreads();
    const float4* P4 = (const float4*)P;
    float4* O4 = (float4*)out_embs + (size_t)bs * (LNUM * KTNUM / 4);
#pragma unroll
    for (int r = 0; r < 2; ++r) {
        int idx = tid + r * 256;
        int l   = idx >> 7;
        int j4  = idx & 127;
        O4[idx] = P4[(((size_t)l * KPAD + toks[l]) * KTNUM >> 2) + j4];
    }
}

extern "C" void kernel_launch(void* const* d_in, const int* in_sizes, int n_in,
                              void* d_out, int out_size, void* d_ws, size_t ws_size,
                              hipStream_t stream) {
    const float* h       = (const float*)d_in[0];
    const float* centers = (const float*)d_in[1];
    const float* W       = (const float*)d_in[2];
    const float* b       = (const float*)d_in[3];

    float* out        = (float*)d_out;
    float* out_tokens = out;
    float* out_embs   = out + (size_t)BNUM * SNUM * LNUM;

    char* ws = (char*)d_ws;
    int*            ws_tokens = (int*)ws;                              // 256 KB @ 0
    float*          c2p       = (float*)(ws + (256 << 10));            // 16 KB
    int*            tie_cnt   = (int*)(ws + (288 << 10));
    int4*           tie_buf   = (int4*)(ws + (320 << 10));             // 1 MB
    float*          P         = (float*)(ws + (1536 << 10));           // 8.39 MB
    unsigned short* cb_hi     = (unsigned short*)(ws + (10496 << 10)); // 6.29 MB
    unsigned short* cb_lo     = (unsigned short*)(ws + (17408 << 10)); // 6.29 MB
    unsigned short* hT2       = (unsigned short*)(ws + (24576 << 10)); // 50.3 MB (2 layers)

    zero_kernel<<<1, 1, 0, stream>>>(tie_cnt);
    prep_kernel<<<dim3(1536), dim3(256), 0, stream>>>(centers, cb_hi, cb_lo);
    c2_kernel<<<dim3(LNUM * KPAD), dim3(64), 0, stream>>>(centers, c2p);
    for (int lpair = 0; lpair < 2; ++lpair) {
        trans_kernel<<<dim3(16, 12, 32), dim3(256), 0, stream>>>(h, hT2, lpair);
        token_kernel<<<dim3(16, 32), dim3(256), 0, stream>>>(hT2, cb_hi, c2p, out_tokens,
                                                             ws_tokens, tie_cnt, tie_buf, lpair);
    }
    rescore_kernel<<<dim3(256), dim3(256), 0, stream>>>(h, centers, tie_cnt, tie_buf,
                                                        out_tokens, ws_tokens);
    proj_kernel<<<dim3(4, 16, LNUM), dim3(256), 0, stream>>>(cb_hi, cb_lo, W, b, P);
    gather_kernel<<<dim3(BNUM * SNUM), dim3(256), 0, stream>>>(P, ws_tokens, out_embs);
}